// Round 1
// baseline (1883.530 us; speedup 1.0000x reference)
//
#include <hip/hip_runtime.h>

typedef unsigned short u16;
typedef unsigned int   u32;
typedef unsigned long long u64;
typedef short s16x8 __attribute__((ext_vector_type(8)));
typedef float f32x4 __attribute__((ext_vector_type(4)));
typedef u32   u32x2 __attribute__((ext_vector_type(2)));
typedef _Float16 f16x2 __attribute__((ext_vector_type(2)));

#define S_LEN 2048
#define BATCH 64
#define H_DIM 300
#define HP    304   // padded N (output) dim
#define KP    320   // padded K (contraction) dim

// ws layout (bytes)
#define OFF_WPAD 0u         // 304*320*2 = 194,560
#define OFF_BIAS 196608u    // 304*4
#define OFF_FLAG 198656u    // 4
#define OFF_H    200704u    // 64*160*4 = 40,960 (f16-pair packed h state)
#define OFF_POOL 278528u    // 2048*304*4 = 2,490,368
#define OFF_WHH  2768896u   // 320*160*4 = 204,800 (f16-pair packed W_hh)
#define OFF_XP   3158016u   // CH*64*304*4 (f32)

__device__ __forceinline__ float bf2f(u16 u){
  union { u32 i; float f; } v; v.i = ((u32)u) << 16; return v.f;
}
__device__ __forceinline__ u16 f2bf(float f){
  u32 i = __float_as_uint(f);
  u32 r = (i + 0x7fffu + ((i >> 16) & 1u)) >> 16;
  return (u16)r;
}
__device__ __forceinline__ f16x2 asH2(u32 u){
  union { u32 u; f16x2 h; } v; v.u = u; return v.h;
}
__device__ __forceinline__ u16 f2h(float f){
  union { _Float16 h; u16 u; } v; v.h = (_Float16)f; return v.u;
}

// v_dot2_f32_f16: c += a.x*b.x + a.y*b.y (f16 inputs, f32 accumulate)
#if __has_builtin(__builtin_amdgcn_fdot2)
#define FD(WU, HU, C) __builtin_amdgcn_fdot2(asH2(WU), asH2(HU), (C), false)
#else
__device__ __forceinline__ float fd_fb(u32 wu, u32 hu, float c){
  const f16x2 w = asH2(wu), h = asH2(hu);
  c = fmaf((float)w.x, (float)h.x, c);
  c = fmaf((float)w.y, (float)h.y, c);
  return c;
}
#define FD(WU, HU, C) fd_fb((WU), (HU), (C))
#endif

// Barrier WITHOUT vmcnt drain: cross-wave LDS handoff only needs the wave's
// own ds ops retired (lgkmcnt(0)) + s_barrier. __syncthreads would emit
// s_waitcnt vmcnt(0) first, synchronously draining the contended global
// atomicMax + xp prefetch every step (~300-600 cy on the serial chain).
// Correctness: atomics/stores only need to complete by kernel end (implicit
// end-of-kernel drain); xnext's consumer gets its own precise vmcnt wait
// from the compiler. sched_barrier(0) pins ds ops around the barrier
// (rule #18: scheduler can otherwise migrate mem ops past inline asm).
#define BAR_LDS() do {                                        \
    __builtin_amdgcn_sched_barrier(0);                        \
    asm volatile("s_waitcnt lgkmcnt(0)" ::: "memory");        \
    __builtin_amdgcn_s_barrier();                             \
    __builtin_amdgcn_sched_barrier(0);                        \
  } while (0)

// ---------------------------------------------------------------------------
// detect: f32 vs bf16 input storage (bf16 emb exponents < 135 always).
// ---------------------------------------------------------------------------
__global__ __launch_bounds__(256) void detect(const u16* __restrict__ emb_raw,
                                              int* __restrict__ flag){
  __shared__ int big;
  if (threadIdx.x == 0) big = 0;
  __syncthreads();
  int loc = 0;
  for (int i = threadIdx.x; i < 1024; i += 256){
    const u32 e = ((u32)emb_raw[i] >> 7) & 0xFFu;
    if (e >= 135u) loc = 1;
  }
  if (loc) atomicOr(&big, 1);
  __syncthreads();
  if (threadIdx.x == 0) *flag = big;   // 1 = f32 inputs, 0 = bf16 inputs
}

// ---------------------------------------------------------------------------
// prep: zero pooled / packed hstate; padded bf16 W_ih [304][320]; fused fp32
// bias; f16-pair packed W_hh [320 rows][160 pairs] (zero padded).
// ---------------------------------------------------------------------------
__global__ __launch_bounds__(256) void prep(
    const void* __restrict__ Wih_raw, const void* __restrict__ Whh_raw,
    const void* __restrict__ bih_raw, const void* __restrict__ bhh_raw,
    const int* __restrict__ flag,
    u16* __restrict__ Wpad, u32* __restrict__ Whh16,
    float* __restrict__ biasp, float* __restrict__ pooled,
    u32* __restrict__ hstate)
{
  const bool isf32 = (*flag != 0);
  const int idx = blockIdx.x * 256 + threadIdx.x;
  if (idx < S_LEN * HP) pooled[idx] = 0.f;
  if (idx < BATCH * 160) hstate[idx] = 0u;
  if (idx < 320 * 160){
    const int r = idx / 160, j = idx % 160;
    const int k = 2 * j;
    float w0 = 0.f, w1 = 0.f;
    if (r < H_DIM){
      if (k < H_DIM)
        w0 = isf32 ? ((const float*)Whh_raw)[r * H_DIM + k]
                   : bf2f(((const u16*)Whh_raw)[r * H_DIM + k]);
      if (k + 1 < H_DIM)
        w1 = isf32 ? ((const float*)Whh_raw)[r * H_DIM + k + 1]
                   : bf2f(((const u16*)Whh_raw)[r * H_DIM + k + 1]);
    }
    Whh16[idx] = (u32)f2h(w0) | ((u32)f2h(w1) << 16);
  }
  if (idx < HP * KP){
    const int n = idx / KP, k = idx % KP;
    u16 v = 0;
    if (n < H_DIM && k < H_DIM){
      v = isf32 ? f2bf(((const float*)Wih_raw)[n * H_DIM + k])
                : ((const u16*)Wih_raw)[n * H_DIM + k];
    }
    Wpad[idx] = v;
  }
  if (idx < HP){
    float bv = 0.f;
    if (idx < H_DIM){
      bv = isf32 ? (((const float*)bih_raw)[idx] + ((const float*)bhh_raw)[idx])
                 : (bf2f(((const u16*)bih_raw)[idx]) + bf2f(((const u16*)bhh_raw)[idx]));
    }
    biasp[idx] = bv;
  }
}

// ---------------------------------------------------------------------------
// xp_gemm: xp[mrel][n] = emb[x[s0*64+mrel]] . W_ih[n,:] + b_ih[n] + b_hh[n]
// One block = 64 m-rows, 4 waves, MFMA 16x16x32 bf16. xp stored f32.
// ---------------------------------------------------------------------------
__global__ __launch_bounds__(256) void xp_gemm(
    const int* __restrict__ x, const void* __restrict__ emb_raw,
    const int* __restrict__ flag,
    const u16* __restrict__ Wpad, const float* __restrict__ biasp,
    float* __restrict__ xp, int s0)
{
  __shared__ u16 A[64 * KP];                 // 40 KB
  const bool isf32 = (*flag != 0);
  const int tid = threadIdx.x;
  const int m0g = s0 * BATCH + blockIdx.x * 64;   // global m of row 0
  const int m0r = blockIdx.x * 64;                // chunk-relative

  for (int t = tid; t < 640; t += 256){
    const int row = t / 10, wd = t % 10;
    *(u32*)&A[row * KP + H_DIM + wd * 2] = 0u;
  }
  for (int t = tid; t < 64 * 75; t += 256){
    const int row = t / 75, off = t % 75;
    const int tok = x[m0g + row];
    u64 pk;
    if (isf32){
      const float4 v = *(const float4*)((const float*)emb_raw + (size_t)tok * H_DIM + off * 4);
      pk = (u64)f2bf(v.x) | ((u64)f2bf(v.y) << 16)
         | ((u64)f2bf(v.z) << 32) | ((u64)f2bf(v.w) << 48);
    } else {
      pk = *(const u64*)((const u16*)emb_raw + (size_t)tok * H_DIM + off * 4);
    }
    *(u64*)&A[row * KP + off * 4] = pk;
  }
  __syncthreads();

  const int wave = tid >> 6, lane = tid & 63;
  const int lm = lane & 15, lq = lane >> 4;

  f32x4 acc[19];
#pragma unroll
  for (int nt = 0; nt < 19; ++nt) acc[nt] = (f32x4){0.f, 0.f, 0.f, 0.f};

#pragma unroll
  for (int ks = 0; ks < 10; ++ks){
    const int k = ks * 32 + lq * 8;
    const s16x8 af = *(const s16x8*)&A[(wave * 16 + lm) * KP + k];
#pragma unroll
    for (int nt = 0; nt < 19; ++nt){
      const s16x8 bf = *(const s16x8*)&Wpad[(nt * 16 + lm) * KP + k];
      acc[nt] = __builtin_amdgcn_mfma_f32_16x16x32_bf16(af, bf, acc[nt], 0, 0, 0);
    }
  }
#pragma unroll
  for (int nt = 0; nt < 19; ++nt){
    const int n = nt * 16 + lm;
    const float bv = biasp[n];
#pragma unroll
    for (int rr = 0; rr < 4; ++rr){
      const int m = m0r + wave * 16 + lq * 4 + rr;
      xp[(size_t)m * HP + n] = acc[nt][rr] + bv;
    }
  }
}

// ---------------------------------------------------------------------------
// recur: one block per batch b. 1024 threads = 16 waves. Wave c owns k-pair
// chunk [10c, 10c+10) (f16 pairs; 160 pairs = K padded 320). Lane l owns
// rows {4l..4l+3, 256+l}. Weights: 50 packed dwords/thread as 25 named
// u32x2 SSA values (fits under the allocator's 84-VGPR budget; bigger sets
// spilled -> L2-BW bound). Dot via v_dot2_f32_f16.
// h kept as f16 pairs in LDS; per-wave broadcast = 5 uniform ds_read_b64.
// In-loop barriers are lgkmcnt-only (BAR_LDS): the global atomicMax to the
// 64-way-contended pooled[] and the xp prefetch stay IN FLIGHT across steps
// instead of being drained 2048x by __syncthreads' vmcnt(0).
// Reduction uses an explicit binary tree (16 seq fadds -> 4-level tree).
// ---------------------------------------------------------------------------
__global__ __launch_bounds__(1024) void recur(
    const float* __restrict__ xp, const u32* __restrict__ Whh16,
    u32* __restrict__ hstate, float* __restrict__ pooled,
    float* __restrict__ dout, int s0, int len)
{
  const int b   = blockIdx.x;
  const int tid = threadIdx.x;
  const int c   = tid >> 6;        // k-pair chunk 0..15
  const int l   = tid & 63;
  const int j0  = c * 10;          // first pair index
  const int r0  = l * 4;           // rows r0..r0+3
  const int r4  = 256 + l;         // 5th row (rows 300..319 zero pad)

  __shared__ float part[16 * 320]; // 20.5 KB
  __shared__ u32 hp[160];          // h as f16 pairs (entries 150..159 pad=0)

  u32x2 qa0,qb0,qc0,qd0,qe0;
  u32x2 qa1,qb1,qc1,qd1,qe1;
  u32x2 qa2,qb2,qc2,qd2,qe2;
  u32x2 qa3,qb3,qc3,qd3,qe3;
  u32x2 qa4,qb4,qc4,qd4,qe4;

#define LOADW(R, ROW) { const u32* wp = Whh16 + (size_t)(ROW) * 160 + j0; \
  qa##R = *(const u32x2*)(wp + 0); qb##R = *(const u32x2*)(wp + 2);       \
  qc##R = *(const u32x2*)(wp + 4); qd##R = *(const u32x2*)(wp + 6);       \
  qe##R = *(const u32x2*)(wp + 8); }
  LOADW(0, r0)
  LOADW(1, r0 + 1)
  LOADW(2, r0 + 2)
  LOADW(3, r0 + 3)
  LOADW(4, r4)
#undef LOADW

  if (tid < 160) hp[tid] = hstate[b * 160 + tid];

  // xp pointer for this batch; row stride per timestep is BATCH*HP floats.
  const float* xptr = xp + (size_t)b * HP;       // row t=0
  float xv = 0.f;
  if (tid < 304) xv = xptr[tid];
  __syncthreads();

  for (int t = 0; t < len; ++t){
    // prefetch next step's xp (strength-reduced pointer, clamped at tail)
    const float* xnp = (t + 1 < len) ? (xptr + (size_t)(BATCH * HP)) : xptr;
    float xnext = 0.f;
    if (tid < 304) xnext = xnp[tid];

    // wave-uniform h broadcast: 5 x ds_read_b64 (8B-aligned, conflict-free)
    const u32x2 h0 = *(const u32x2*)&hp[j0 + 0];
    const u32x2 h1 = *(const u32x2*)&hp[j0 + 2];
    const u32x2 h2 = *(const u32x2*)&hp[j0 + 4];
    const u32x2 h3 = *(const u32x2*)&hp[j0 + 6];
    const u32x2 h4 = *(const u32x2*)&hp[j0 + 8];

    float s0v, s1v, s2v, s3v, s4v;
#define DOTROW(R, DST) { float s = 0.f;                              \
    s = FD(qa##R.x, h0.x, s); s = FD(qa##R.y, h0.y, s);              \
    s = FD(qb##R.x, h1.x, s); s = FD(qb##R.y, h1.y, s);              \
    s = FD(qc##R.x, h2.x, s); s = FD(qc##R.y, h2.y, s);              \
    s = FD(qd##R.x, h3.x, s); s = FD(qd##R.y, h3.y, s);              \
    s = FD(qe##R.x, h4.x, s); s = FD(qe##R.y, h4.y, s); DST = s; }
    DOTROW(0, s0v)
    DOTROW(1, s1v)
    DOTROW(2, s2v)
    DOTROW(3, s3v)
    DOTROW(4, s4v)
#undef DOTROW

    *(f32x4*)&part[c * 320 + r0] = (f32x4){s0v, s1v, s2v, s3v};
    part[c * 320 + r4] = s4v;
    BAR_LDS();                       // partials ready (no vmcnt drain)

    if (tid < 304){
      float p[16];
#pragma unroll
      for (int cc = 0; cc < 16; ++cc) p[cc] = part[cc * 320 + tid];
      // binary-tree sum: dependent chain 4 levels instead of 16
#pragma unroll
      for (int st = 1; st < 16; st <<= 1){
#pragma unroll
        for (int i = 0; i < 16; i += 2 * st) p[i] += p[i + st];
      }
      const float sum = xv + p[0];
      const float h = fmaxf(sum, 0.f);
      const int s = s0 + t;
      if (tid < H_DIM){
        atomicMax((u32*)(pooled + (size_t)s * HP + tid), __float_as_uint(h));
        if (s == S_LEN - 1) dout[S_LEN * 2 + b * H_DIM + tid] = h;
      }
      ((u16*)hp)[tid] = f2h(h);
      xv = xnext;
    }
    xptr = xnp;
    BAR_LDS();                       // h ready (no vmcnt drain)
  }
  if (tid < 160) hstate[b * 160 + tid] = hp[tid];
}

// ---------------------------------------------------------------------------
// outproj: out[s][c] = sum_i pooled[s][i] * W_out[c][i] + b_out[c]  (f32 out)
// ---------------------------------------------------------------------------
__global__ __launch_bounds__(128) void outproj(
    const float* __restrict__ pooled, const void* __restrict__ Wout_raw,
    const void* __restrict__ bout_raw, const int* __restrict__ flag,
    float* __restrict__ dout)
{
  const bool isf32 = (*flag != 0);
  const int s = blockIdx.x * 128 + threadIdx.x;   // 0..2047
  float a0, a1;
  if (isf32){ a0 = ((const float*)bout_raw)[0]; a1 = ((const float*)bout_raw)[1]; }
  else      { a0 = bf2f(((const u16*)bout_raw)[0]); a1 = bf2f(((const u16*)bout_raw)[1]); }
  for (int i = 0; i < H_DIM; ++i){
    const float p = pooled[(size_t)s * HP + i];
    float w0, w1;
    if (isf32){ w0 = ((const float*)Wout_raw)[i]; w1 = ((const float*)Wout_raw)[H_DIM + i]; }
    else      { w0 = bf2f(((const u16*)Wout_raw)[i]); w1 = bf2f(((const u16*)Wout_raw)[H_DIM + i]); }
    a0 = fmaf(p, w0, a0);
    a1 = fmaf(p, w1, a1);
  }
  dout[s * 2 + 0] = a0;
  dout[s * 2 + 1] = a1;
}

// ---------------------------------------------------------------------------
extern "C" void kernel_launch(void* const* d_in, const int* in_sizes, int n_in,
                              void* d_out, int out_size, void* d_ws, size_t ws_size,
                              hipStream_t stream)
{
  const int* x  = (const int*)d_in[0];
  const void* emb  = d_in[1];
  const void* Wih  = d_in[2];
  const void* Whh  = d_in[3];
  const void* bih  = d_in[4];
  const void* bhh  = d_in[5];
  const void* Wout = d_in[6];
  const void* bout = d_in[7];
  float* out = (float*)d_out;

  char* ws = (char*)d_ws;
  u16*   Wpad   = (u16*)(ws + OFF_WPAD);
  float* biasp  = (float*)(ws + OFF_BIAS);
  int*   flag   = (int*)(ws + OFF_FLAG);
  u32*   hstate = (u32*)(ws + OFF_H);
  float* pooled = (float*)(ws + OFF_POOL);
  u32*   Whh16  = (u32*)(ws + OFF_WHH);
  float* xp     = (float*)(ws + OFF_XP);

  // choose chunk size (steps) so OFF_XP + CH*64*304*4 fits in ws_size
  const size_t per_step = (size_t)BATCH * HP * 4;   // 77,824 B
  int CH = 16;
  const int cands[8] = {2048, 1024, 512, 256, 128, 64, 32, 16};
  for (int i = 0; i < 8; ++i){
    if ((size_t)OFF_XP + (size_t)cands[i] * per_step <= ws_size){ CH = cands[i]; break; }
  }
  const int nchunks = S_LEN / CH;

  detect<<<1, 256, 0, stream>>>((const u16*)emb, flag);
  prep<<<2432, 256, 0, stream>>>(Wih, Whh, bih, bhh, flag, Wpad, Whh16,
                                 biasp, pooled, hstate);
  for (int k = 0; k < nchunks; ++k){
    const int s0 = k * CH;
    xp_gemm<<<CH, 256, 0, stream>>>(x, emb, flag, Wpad, biasp, xp, s0);
    recur<<<64, 1024, 0, stream>>>(xp, Whh16, hstate, pooled, out, s0, CH);
  }
  outproj<<<16, 128, 0, stream>>>(pooled, Wout, bout, flag, out);
}